// Round 3
// baseline (1137.884 us; speedup 1.0000x reference)
//
#include <hip/hip_runtime.h>

#define HID 2048
#define INTER 1408
#define NEXP 14
#define SINTER 2816
#define TTOK 2048
#define GBM 384

#define RGLU (22 * NEXP)   // 308 routed glu blocks (22 n-tiles x 14 experts)
#define SGLU_N 44          // 2816/64 shared glu n-tiles
#define SGLU_M 6           // ceil(2048/384) shared m-slices
#define DWN_N 32           // 2048/64 down n-tiles
#define SDWN (DWN_N * 6)   // 192 shared down blocks

typedef short bf16x8 __attribute__((ext_vector_type(8)));
typedef float f32x4 __attribute__((ext_vector_type(4)));
typedef unsigned short u16x8 __attribute__((ext_vector_type(8)));

__device__ __forceinline__ unsigned short f2bf(float f) {
    __bf16 b = (__bf16)f;
    return __builtin_bit_cast(unsigned short, b);
}
__device__ __forceinline__ float bf2f(unsigned short u) {
    unsigned v = (unsigned)u << 16;
    return __builtin_bit_cast(float, v);
}
// XOR swizzle for tiles with 128B row stride
__device__ __forceinline__ unsigned swz(unsigned b) { return b ^ (((b >> 7) & 7u) << 4); }

__global__ void k_zero(int* cnt) {
    if ((int)threadIdx.x < NEXP) cnt[threadIdx.x] = 0;
}

__global__ __launch_bounds__(256) void k_xcvt(const float* __restrict__ x,
                                              unsigned short* __restrict__ xb) {
    size_t i = ((size_t)blockIdx.x * 256 + threadIdx.x) * 8;
    float4 a = *(const float4*)(x + i);
    float4 b = *(const float4*)(x + i + 4);
    u16x8 v;
    v[0] = f2bf(a.x); v[1] = f2bf(a.y); v[2] = f2bf(a.z); v[3] = f2bf(a.w);
    v[4] = f2bf(b.x); v[5] = f2bf(b.y); v[6] = f2bf(b.z); v[7] = f2bf(b.w);
    *(u16x8*)(xb + i) = v;
}

__global__ __launch_bounds__(256) void k_router(
    const float* __restrict__ x,
    const float* __restrict__ gate_w, const float* __restrict__ cls_w,
    const float* __restrict__ escale, const float* __restrict__ ebias,
    int* __restrict__ cnt, int* __restrict__ etok, float* __restrict__ ew) {
    const int lane = threadIdx.x & 63;
    const int tok = blockIdx.x * 4 + (threadIdx.x >> 6);
    const float* xr = x + (size_t)tok * HID;
    float xv[32];
#pragma unroll
    for (int i = 0; i < 32; i++) xv[i] = xr[lane + 64 * i];

    float sc[NEXP];
    float mx = 0.f;
#pragma unroll
    for (int e = 0; e < NEXP; e++) {
        const float* cw = cls_w + (size_t)e * HID;
        const float* gw = gate_w + (size_t)e * HID;
        float pc = 0.f, pg = 0.f;
#pragma unroll
        for (int i = 0; i < 32; i++) {
            float v = xv[i];
            pc = fmaf(v, cw[lane + 64 * i], pc);
            pg = fmaf(v, gw[lane + 64 * i], pg);
        }
#pragma unroll
        for (int o = 32; o >= 1; o >>= 1) {
            pc += __shfl_xor(pc, o);
            pg += __shfl_xor(pg, o);
        }
        float lg = pc * (pg / (1.f + __expf(-pg)));
        sc[e] = fabsf(lg);
        mx = fmaxf(mx, sc[e]);
    }
    float s = 0.f;
#pragma unroll
    for (int e = 0; e < NEXP; e++) { sc[e] = __expf(sc[e] - mx); s += sc[e]; }
    float inv = 1.f / s;
    int i1 = -1, i2 = -1;
    float b1 = -1e30f, b2 = -1e30f, v1 = 0.f, v2 = 0.f;
#pragma unroll
    for (int e = 0; e < NEXP; e++) {
        float sv = sc[e] * inv;
        float b = sv + ebias[e];
        if (b > b1) { b2 = b1; i2 = i1; v2 = v1; b1 = b; i1 = e; v1 = sv; }
        else if (b > b2) { b2 = b; i2 = e; v2 = sv; }
    }
    if (lane == 0) {
        float w1 = 1.f + v1 * escale[i1];
        float w2 = 1.f + v2 * escale[i2];
        int p1 = atomicAdd(&cnt[i1], 1);
        etok[i1 * TTOK + p1] = tok * 2;     ew[i1 * TTOK + p1] = w1;
        int p2 = atomicAdd(&cnt[i2], 1);
        etok[i2 * TTOK + p2] = tok * 2 + 1; ew[i2 * TTOK + p2] = w2;
    }
}

__global__ void k_offsets(const int* __restrict__ cnt, int* __restrict__ offs) {
    if (threadIdx.x == 0) {
        int a = 0;
        for (int e = 0; e < NEXP; e++) { offs[e] = a; a += cnt[e]; }
    }
}

// Fused gate+up GEMM (routed experts + shared expert), BM=384, BN=64 per matrix,
// BK=64, 512 threads / 8 waves. In-block m-loop keeps weight re-reads L2-warm.
__global__ __launch_bounds__(512) void k_glu2(
    const unsigned short* __restrict__ xb,
    const float* __restrict__ wg, const float* __restrict__ wu,
    const float* __restrict__ sg, const float* __restrict__ su,
    unsigned short* __restrict__ abuf, unsigned short* __restrict__ hbuf,
    const int* __restrict__ cnt, const int* __restrict__ offs,
    const int* __restrict__ etok) {
    __shared__ alignas(16) unsigned short sA[GBM * 64];   // 48 KB
    __shared__ alignas(16) unsigned short sBg[64 * 64];   // 8 KB
    __shared__ alignas(16) unsigned short sBu[64 * 64];   // 8 KB

    const int bx = blockIdx.x;
    const int t = threadIdx.x;
    const bool routed = bx < RGLU;
    int n0, m_start, m_stop, obase, Ntot;
    const float *Bg, *Bu;
    unsigned short* outp;
    const int* etk = nullptr;
    if (routed) {
        int e = bx / 22; n0 = (bx % 22) * 64;
        int M = cnt[e];
        if (M <= 0) return;
        m_start = 0; m_stop = M; obase = offs[e]; Ntot = INTER;
        Bg = wg + ((size_t)e * INTER + n0) * HID;
        Bu = wu + ((size_t)e * INTER + n0) * HID;
        outp = abuf; etk = etok + e * TTOK;
    } else {
        int sx = bx - RGLU;
        n0 = (sx % SGLU_N) * 64;
        int ms = sx / SGLU_N;
        m_start = ms * GBM; m_stop = min(TTOK, m_start + GBM);
        obase = 0; Ntot = SINTER;
        Bg = sg + (size_t)n0 * HID;
        Bu = su + (size_t)n0 * HID;
        outp = hbuf;
    }

    // B staging: 2 x 16B fp32 chunks per thread per matrix
    const float* srcG[2]; const float* srcU[2]; unsigned wBo[2];
#pragma unroll
    for (int q = 0; q < 2; q++) {
        int idx = q * 512 + t;
        int row = idx >> 4, c4 = idx & 15;
        srcG[q] = Bg + (size_t)row * HID + c4 * 4;
        srcU[q] = Bu + (size_t)row * HID + c4 * 4;
        wBo[q] = swz((unsigned)(row * 128 + c4 * 8));
    }

    const int lane = t & 63;
    const int w = t >> 6;
    const int fr = lane & 15, fo = lane >> 4;

    unsigned aoff[3][2], boff[4][2];
#pragma unroll
    for (int mi = 0; mi < 3; mi++)
#pragma unroll
        for (int ks = 0; ks < 2; ks++)
            aoff[mi][ks] = swz((unsigned)((w * 48 + mi * 16 + fr) * 128 + ks * 64 + fo * 16));
#pragma unroll
    for (int nj = 0; nj < 4; nj++)
#pragma unroll
        for (int ks = 0; ks < 2; ks++)
            boff[nj][ks] = swz((unsigned)((nj * 16 + fr) * 128 + ks * 64 + fo * 16));

    for (int m0 = m_start; m0 < m_stop; m0 += GBM) {
        int rv = m_stop - m0; if (rv > GBM) rv = GBM;
        const unsigned short* srcA[6]; unsigned wAo[6];
#pragma unroll
        for (int p = 0; p < 6; p++) {
            int r = p * 64 + (t >> 3);
            int rr = r < rv ? r : rv - 1;
            int row = m0 + rr;
            int tok = routed ? (etk[row] >> 1) : row;
            srcA[p] = xb + (size_t)tok * HID + (t & 7) * 8;
            wAo[p] = swz((unsigned)(r * 128 + (t & 7) * 16));
        }

        uint4 ra[6]; float4 rg[2]; float4 ru[2];
        auto load = [&](int k0) {
#pragma unroll
            for (int p = 0; p < 6; p++) ra[p] = *(const uint4*)(srcA[p] + k0);
#pragma unroll
            for (int q = 0; q < 2; q++) { rg[q] = *(const float4*)(srcG[q] + k0); ru[q] = *(const float4*)(srcU[q] + k0); }
        };
        auto store = [&]() {
#pragma unroll
            for (int p = 0; p < 6; p++) *(uint4*)((char*)sA + wAo[p]) = ra[p];
#pragma unroll
            for (int q = 0; q < 2; q++) {
                ushort4 vg, vu;
                vg.x = f2bf(rg[q].x); vg.y = f2bf(rg[q].y); vg.z = f2bf(rg[q].z); vg.w = f2bf(rg[q].w);
                vu.x = f2bf(ru[q].x); vu.y = f2bf(ru[q].y); vu.z = f2bf(ru[q].z); vu.w = f2bf(ru[q].w);
                *(ushort4*)((char*)sBg + wBo[q]) = vg;
                *(ushort4*)((char*)sBu + wBo[q]) = vu;
            }
        };

        f32x4 ag[3][4], au[3][4];
#pragma unroll
        for (int mi = 0; mi < 3; mi++)
#pragma unroll
            for (int nj = 0; nj < 4; nj++) { ag[mi][nj] = {0.f,0.f,0.f,0.f}; au[mi][nj] = {0.f,0.f,0.f,0.f}; }

        load(0); store(); __syncthreads();
        for (int kk = 0; kk < HID / 64; ++kk) {
            if (kk + 1 < HID / 64) load((kk + 1) * 64);
#pragma unroll
            for (int ks = 0; ks < 2; ++ks) {
                bf16x8 af[3], gf[4], uf[4];
#pragma unroll
                for (int mi = 0; mi < 3; mi++)
                    af[mi] = *(const bf16x8*)((const char*)sA + aoff[mi][ks]);
#pragma unroll
                for (int nj = 0; nj < 4; nj++) {
                    gf[nj] = *(const bf16x8*)((const char*)sBg + boff[nj][ks]);
                    uf[nj] = *(const bf16x8*)((const char*)sBu + boff[nj][ks]);
                }
#pragma unroll
                for (int mi = 0; mi < 3; mi++)
#pragma unroll
                    for (int nj = 0; nj < 4; nj++) {
                        ag[mi][nj] = __builtin_amdgcn_mfma_f32_16x16x32_bf16(af[mi], gf[nj], ag[mi][nj], 0, 0, 0);
                        au[mi][nj] = __builtin_amdgcn_mfma_f32_16x16x32_bf16(af[mi], uf[nj], au[mi][nj], 0, 0, 0);
                    }
            }
            __syncthreads();
            if (kk + 1 < HID / 64) store();
            __syncthreads();
        }

        // epilogue: h = silu(g)*u, stage bf16 tile [384][64] in sA, coalesced sweep
#pragma unroll
        for (int mi = 0; mi < 3; mi++)
#pragma unroll
            for (int j = 0; j < 4; j++) {
                int r = w * 48 + mi * 16 + fo * 4 + j;
#pragma unroll
                for (int nj = 0; nj < 4; nj++) {
                    int c = nj * 16 + fr;
                    float g = ag[mi][nj][j];
                    float u = au[mi][nj][j];
                    float h = (g / (1.f + __expf(-g))) * u;
                    *(unsigned short*)((char*)sA + swz((unsigned)(r * 128 + c * 2))) = f2bf(h);
                }
            }
        __syncthreads();
#pragma unroll
        for (int p = 0; p < 6; p++) {
            int r = p * 64 + (t >> 3);
            if (r < rv) {
                uint4 v = *(const uint4*)((const char*)sA + swz((unsigned)(r * 128 + (t & 7) * 16)));
                *(uint4*)(outp + (size_t)(obase + m0 + r) * Ntot + n0 + (t & 7) * 8) = v;
            }
        }
        __syncthreads();
    }
}

// Fused down GEMM (shared + routed). BM=384, BN=64, BK=64, 512 threads.
__global__ __launch_bounds__(512) void k_down2(
    const unsigned short* __restrict__ abuf, const unsigned short* __restrict__ hbuf,
    const float* __restrict__ wd, const float* __restrict__ sd,
    float* __restrict__ out, unsigned short* __restrict__ slots,
    const int* __restrict__ cnt, const int* __restrict__ offs,
    const int* __restrict__ etok, const float* __restrict__ ew) {
    __shared__ alignas(16) unsigned short sA[GBM * 64];   // 48 KB
    __shared__ alignas(16) unsigned short sB[64 * 64];    // 8 KB

    const int bx = blockIdx.x;
    const int t = threadIdx.x;
    const bool shared_e = bx < SDWN;
    int n0, m_start, m_stop, K, KT;
    const float* B;
    const unsigned short* Abuf;
    size_t arow0 = 0;
    const int* etk = nullptr; const float* ewe = nullptr;
    if (shared_e) {
        n0 = (bx % DWN_N) * 64;
        int ms = bx / DWN_N;
        m_start = ms * GBM; m_stop = min(TTOK, m_start + GBM);
        K = SINTER; KT = SINTER / 64;
        B = sd + (size_t)n0 * SINTER;
        Abuf = hbuf;
    } else {
        int rx = bx - SDWN;
        int e = rx / DWN_N; n0 = (rx % DWN_N) * 64;
        int M = cnt[e];
        if (M <= 0) return;
        m_start = 0; m_stop = M;
        K = INTER; KT = INTER / 64;
        B = wd + ((size_t)e * HID + n0) * INTER;
        Abuf = abuf; arow0 = offs[e];
        etk = etok + e * TTOK; ewe = ew + e * TTOK;
    }

    const float* srcB[2]; unsigned wBo[2];
#pragma unroll
    for (int q = 0; q < 2; q++) {
        int idx = q * 512 + t;
        int row = idx >> 4, c4 = idx & 15;
        srcB[q] = B + (size_t)row * K + c4 * 4;
        wBo[q] = swz((unsigned)(row * 128 + c4 * 8));
    }

    const int lane = t & 63;
    const int w = t >> 6;
    const int fr = lane & 15, fo = lane >> 4;

    unsigned aoff[3][2], boff[4][2];
#pragma unroll
    for (int mi = 0; mi < 3; mi++)
#pragma unroll
        for (int ks = 0; ks < 2; ks++)
            aoff[mi][ks] = swz((unsigned)((w * 48 + mi * 16 + fr) * 128 + ks * 64 + fo * 16));
#pragma unroll
    for (int nj = 0; nj < 4; nj++)
#pragma unroll
        for (int ks = 0; ks < 2; ks++)
            boff[nj][ks] = swz((unsigned)((nj * 16 + fr) * 128 + ks * 64 + fo * 16));

    for (int m0 = m_start; m0 < m_stop; m0 += GBM) {
        int rv = m_stop - m0; if (rv > GBM) rv = GBM;
        const unsigned short* srcA[6]; unsigned wAo[6];
#pragma unroll
        for (int p = 0; p < 6; p++) {
            int r = p * 64 + (t >> 3);
            int rr = r < rv ? r : rv - 1;
            srcA[p] = Abuf + (arow0 + m0 + rr) * (size_t)K + (t & 7) * 8;
            wAo[p] = swz((unsigned)(r * 128 + (t & 7) * 16));
        }

        uint4 ra[6]; float4 rb[2];
        auto load = [&](int k0) {
#pragma unroll
            for (int p = 0; p < 6; p++) ra[p] = *(const uint4*)(srcA[p] + k0);
#pragma unroll
            for (int q = 0; q < 2; q++) rb[q] = *(const float4*)(srcB[q] + k0);
        };
        auto store = [&]() {
#pragma unroll
            for (int p = 0; p < 6; p++) *(uint4*)((char*)sA + wAo[p]) = ra[p];
#pragma unroll
            for (int q = 0; q < 2; q++) {
                ushort4 v;
                v.x = f2bf(rb[q].x); v.y = f2bf(rb[q].y); v.z = f2bf(rb[q].z); v.w = f2bf(rb[q].w);
                *(ushort4*)((char*)sB + wBo[q]) = v;
            }
        };

        f32x4 ac[3][4];
#pragma unroll
        for (int mi = 0; mi < 3; mi++)
#pragma unroll
            for (int nj = 0; nj < 4; nj++) ac[mi][nj] = {0.f,0.f,0.f,0.f};

        load(0); store(); __syncthreads();
        for (int kk = 0; kk < KT; ++kk) {
            if (kk + 1 < KT) load((kk + 1) * 64);
#pragma unroll
            for (int ks = 0; ks < 2; ++ks) {
                bf16x8 af[3], bf[4];
#pragma unroll
                for (int mi = 0; mi < 3; mi++)
                    af[mi] = *(const bf16x8*)((const char*)sA + aoff[mi][ks]);
#pragma unroll
                for (int nj = 0; nj < 4; nj++)
                    bf[nj] = *(const bf16x8*)((const char*)sB + boff[nj][ks]);
#pragma unroll
                for (int mi = 0; mi < 3; mi++)
#pragma unroll
                    for (int nj = 0; nj < 4; nj++)
                        ac[mi][nj] = __builtin_amdgcn_mfma_f32_16x16x32_bf16(af[mi], bf[nj], ac[mi][nj], 0, 0, 0);
            }
            __syncthreads();
            if (kk + 1 < KT) store();
            __syncthreads();
        }

        if (shared_e) {
            // z written straight to out (fp32)
#pragma unroll
            for (int mi = 0; mi < 3; mi++)
#pragma unroll
                for (int j = 0; j < 4; j++) {
                    int r = w * 48 + mi * 16 + fo * 4 + j;
                    if (r < rv) {
                        float* orow = out + (size_t)(m0 + r) * HID + n0;
#pragma unroll
                        for (int nj = 0; nj < 4; nj++)
                            orow[nj * 16 + fr] = ac[mi][nj][j];
                    }
                }
        } else {
            // scale by combine weight, stage bf16 tile, sweep to per-(tok,slot) rows
#pragma unroll
            for (int mi = 0; mi < 3; mi++)
#pragma unroll
                for (int j = 0; j < 4; j++) {
                    int r = w * 48 + mi * 16 + fo * 4 + j;
                    if (r < rv) {
                        float wt = ewe[m0 + r];
#pragma unroll
                        for (int nj = 0; nj < 4; nj++)
                            *(unsigned short*)((char*)sA + swz((unsigned)(r * 128 + (nj * 16 + fr) * 2))) =
                                f2bf(ac[mi][nj][j] * wt);
                    }
                }
            __syncthreads();
#pragma unroll
            for (int p = 0; p < 6; p++) {
                int r = p * 64 + (t >> 3);
                if (r < rv) {
                    int entry = etk[m0 + r];
                    uint4 v = *(const uint4*)((const char*)sA + swz((unsigned)(r * 128 + (t & 7) * 16)));
                    *(uint4*)(slots + ((size_t)(entry & 1) * TTOK + (entry >> 1)) * HID + n0 + (t & 7) * 8) = v;
                }
            }
            __syncthreads();
        }
    }
}

__global__ __launch_bounds__(256) void k_final(float* __restrict__ out,
                                               const unsigned short* __restrict__ slots) {
    size_t i = ((size_t)blockIdx.x * 256 + threadIdx.x) * 8;
    u16x8 s0 = *(const u16x8*)(slots + i);
    u16x8 s1 = *(const u16x8*)(slots + (size_t)TTOK * HID + i);
    float4 o0 = *(float4*)(out + i);
    float4 o1 = *(float4*)(out + i + 4);
    o0.x += bf2f(s0[0]) + bf2f(s1[0]);
    o0.y += bf2f(s0[1]) + bf2f(s1[1]);
    o0.z += bf2f(s0[2]) + bf2f(s1[2]);
    o0.w += bf2f(s0[3]) + bf2f(s1[3]);
    o1.x += bf2f(s0[4]) + bf2f(s1[4]);
    o1.y += bf2f(s0[5]) + bf2f(s1[5]);
    o1.z += bf2f(s0[6]) + bf2f(s1[6]);
    o1.w += bf2f(s0[7]) + bf2f(s1[7]);
    *(float4*)(out + i) = o0;
    *(float4*)(out + i + 4) = o1;
}

extern "C" void kernel_launch(void* const* d_in, const int* in_sizes, int n_in,
                              void* d_out, int out_size, void* d_ws, size_t ws_size,
                              hipStream_t stream) {
    const float* x = (const float*)d_in[0];
    const float* gate_w = (const float*)d_in[1];
    const float* cls_w = (const float*)d_in[2];
    const float* escale = (const float*)d_in[3];
    const float* ebias = (const float*)d_in[4];
    const float* wg = (const float*)d_in[5];
    const float* wu = (const float*)d_in[6];
    const float* wd = (const float*)d_in[7];
    const float* sg = (const float*)d_in[8];
    const float* su = (const float*)d_in[9];
    const float* sd = (const float*)d_in[10];
    float* out = (float*)d_out;

    char* ws = (char*)d_ws;
    size_t o = 0;
    auto alloc = [&](size_t bytes) {
        char* p = ws + o;
        o += (bytes + 255) & ~(size_t)255;
        return p;
    };
    unsigned short* xb    = (unsigned short*)alloc((size_t)TTOK * HID * 2);        // 8 MB
    unsigned short* hbuf  = (unsigned short*)alloc((size_t)TTOK * SINTER * 2);     // 11.5 MB
    unsigned short* abuf  = (unsigned short*)alloc((size_t)2 * TTOK * INTER * 2);  // 11.5 MB
    unsigned short* slots = (unsigned short*)alloc((size_t)2 * TTOK * HID * 2);    // 16 MB
    int* cnt              = (int*)alloc(256);
    int* offs             = (int*)alloc(256);
    int* etok             = (int*)alloc((size_t)NEXP * TTOK * 4);
    float* ew             = (float*)alloc((size_t)NEXP * TTOK * 4);

    k_zero<<<1, 64, 0, stream>>>(cnt);
    k_xcvt<<<2048, 256, 0, stream>>>(x, xb);
    k_router<<<512, 256, 0, stream>>>(x, gate_w, cls_w, escale, ebias, cnt, etok, ew);
    k_offsets<<<1, 64, 0, stream>>>(cnt, offs);
    k_glu2<<<RGLU + SGLU_N * SGLU_M, 512, 0, stream>>>(
        xb, wg, wu, sg, su, abuf, hbuf, cnt, offs, etok);
    k_down2<<<SDWN + DWN_N * NEXP, 512, 0, stream>>>(
        abuf, hbuf, wd, sd, out, slots, cnt, offs, etok, ew);
    k_final<<<2048, 256, 0, stream>>>(out, slots);
}

// Round 4
// 678.334 us; speedup vs baseline: 1.6775x; 1.6775x over previous
//
#include <hip/hip_runtime.h>

#define HID 2048
#define INTER 1408
#define NEXP 14
#define SINTER 2816
#define TTOK 2048

#define RGLU_NT 22              // 1408/64 routed glu n-tiles
#define RGLU (RGLU_NT * NEXP)   // 308
#define SGLU_N 44               // 2816/64 shared glu n-tiles
#define SGLU_M 6                // ceil(2048/384)
#define DWN_NT 16               // 2048/128 down n-tiles
#define RDWN (DWN_NT * NEXP)    // 224
#define SDWN_M 6

typedef short bf16x8 __attribute__((ext_vector_type(8)));
typedef float f32x4 __attribute__((ext_vector_type(4)));
typedef unsigned short u16x8 __attribute__((ext_vector_type(8)));

__device__ __forceinline__ unsigned short f2bf(float f) {
    __bf16 b = (__bf16)f;
    return __builtin_bit_cast(unsigned short, b);
}
__device__ __forceinline__ float bf2f(unsigned short u) {
    unsigned v = (unsigned)u << 16;
    return __builtin_bit_cast(float, v);
}
// XOR swizzle for tiles with 128B row stride
__device__ __forceinline__ unsigned swz(unsigned b) { return b ^ (((b >> 7) & 7u) << 4); }

// async global->LDS, 16B per lane; LDS dest = wave-uniform base + lane*16
__device__ __forceinline__ void gload16(const void* g, void* l) {
    __builtin_amdgcn_global_load_lds((__attribute__((address_space(1))) void*)g,
                                     (__attribute__((address_space(3))) void*)l, 16, 0, 0);
}

__global__ void k_zero(int* cnt) {
    if ((int)threadIdx.x < NEXP) cnt[threadIdx.x] = 0;
}

__global__ __launch_bounds__(256) void k_xcvt(const float* __restrict__ x,
                                              unsigned short* __restrict__ xb) {
    size_t i = ((size_t)blockIdx.x * 256 + threadIdx.x) * 8;
    float4 a = *(const float4*)(x + i);
    float4 b = *(const float4*)(x + i + 4);
    u16x8 v;
    v[0] = f2bf(a.x); v[1] = f2bf(a.y); v[2] = f2bf(a.z); v[3] = f2bf(a.w);
    v[4] = f2bf(b.x); v[5] = f2bf(b.y); v[6] = f2bf(b.z); v[7] = f2bf(b.w);
    *(u16x8*)(xb + i) = v;
}

__global__ __launch_bounds__(256) void k_router(
    const float* __restrict__ x,
    const float* __restrict__ gate_w, const float* __restrict__ cls_w,
    const float* __restrict__ escale, const float* __restrict__ ebias,
    int* __restrict__ cnt, int* __restrict__ etok, float* __restrict__ ew) {
    const int lane = threadIdx.x & 63;
    const int tok = blockIdx.x * 4 + (threadIdx.x >> 6);
    const float* xr = x + (size_t)tok * HID;
    float xv[32];
#pragma unroll
    for (int i = 0; i < 32; i++) xv[i] = xr[lane + 64 * i];

    float sc[NEXP];
    float mx = 0.f;
#pragma unroll
    for (int e = 0; e < NEXP; e++) {
        const float* cw = cls_w + (size_t)e * HID;
        const float* gw = gate_w + (size_t)e * HID;
        float pc = 0.f, pg = 0.f;
#pragma unroll
        for (int i = 0; i < 32; i++) {
            float v = xv[i];
            pc = fmaf(v, cw[lane + 64 * i], pc);
            pg = fmaf(v, gw[lane + 64 * i], pg);
        }
#pragma unroll
        for (int o = 32; o >= 1; o >>= 1) {
            pc += __shfl_xor(pc, o);
            pg += __shfl_xor(pg, o);
        }
        float lg = pc * (pg / (1.f + __expf(-pg)));
        sc[e] = fabsf(lg);
        mx = fmaxf(mx, sc[e]);
    }
    float s = 0.f;
#pragma unroll
    for (int e = 0; e < NEXP; e++) { sc[e] = __expf(sc[e] - mx); s += sc[e]; }
    float inv = 1.f / s;
    int i1 = -1, i2 = -1;
    float b1 = -1e30f, b2 = -1e30f, v1 = 0.f, v2 = 0.f;
#pragma unroll
    for (int e = 0; e < NEXP; e++) {
        float sv = sc[e] * inv;
        float b = sv + ebias[e];
        if (b > b1) { b2 = b1; i2 = i1; v2 = v1; b1 = b; i1 = e; v1 = sv; }
        else if (b > b2) { b2 = b; i2 = e; v2 = sv; }
    }
    if (lane == 0) {
        float w1 = 1.f + v1 * escale[i1];
        float w2 = 1.f + v2 * escale[i2];
        int p1 = atomicAdd(&cnt[i1], 1);
        etok[i1 * TTOK + p1] = tok * 2;     ew[i1 * TTOK + p1] = w1;
        int p2 = atomicAdd(&cnt[i2], 1);
        etok[i2 * TTOK + p2] = tok * 2 + 1; ew[i2 * TTOK + p2] = w2;
    }
}

__global__ void k_offsets(const int* __restrict__ cnt, int* __restrict__ offs) {
    if (threadIdx.x == 0) {
        int a = 0;
        for (int e = 0; e < NEXP; e++) { offs[e] = a; a += cnt[e]; }
    }
}

// Fused gate+up GEMM. BM=384, BN=64 (per matrix), BK=64, 1024 thr / 16 waves (8m x 2n).
// A: bf16 via global_load_lds (pre-swizzled source). B: fp32 -> bf16 phase-local regs.
__global__ __launch_bounds__(1024) void k_glu3(
    const unsigned short* __restrict__ xb,
    const float* __restrict__ wg, const float* __restrict__ wu,
    const float* __restrict__ sg, const float* __restrict__ su,
    unsigned short* __restrict__ abuf, unsigned short* __restrict__ hbuf,
    const int* __restrict__ cnt, const int* __restrict__ offs,
    const int* __restrict__ etok) {
    __shared__ alignas(16) unsigned short sA[384 * 64];   // 48 KB
    __shared__ alignas(16) unsigned short sBg[64 * 64];   // 8 KB
    __shared__ alignas(16) unsigned short sBu[64 * 64];   // 8 KB

    const int bx = blockIdx.x;
    const int t = threadIdx.x;
    const int lane = t & 63;
    const int w = t >> 6;            // 0..15
    const int wm = w >> 1, wn = w & 1;
    const int fr = lane & 15, fo = lane >> 4;

    const bool routed = bx < RGLU;
    int n0, m_start, m_stop, obase, Ntot;
    const float *Bg, *Bu;
    unsigned short* outp;
    const int* etk = nullptr;
    if (routed) {
        int e = bx / RGLU_NT; n0 = (bx % RGLU_NT) * 64;
        int M = cnt[e];
        if (M <= 0) return;
        m_start = 0; m_stop = M; obase = offs[e]; Ntot = INTER;
        Bg = wg + ((size_t)e * INTER + n0) * HID;
        Bu = wu + ((size_t)e * INTER + n0) * HID;
        outp = abuf; etk = etok + e * TTOK;
    } else {
        int sx = bx - RGLU;
        n0 = (sx % SGLU_N) * 64;
        m_start = (sx / SGLU_N) * 384;
        m_stop = min(TTOK, m_start + 384);
        obase = 0; Ntot = SINTER;
        Bg = sg + (size_t)n0 * HID;
        Bu = su + (size_t)n0 * HID;
        outp = hbuf;
    }

    // B staging: thread -> row t>>4 (0..63), 4 floats at (t&15)*4; 8B bf16 ds_write
    const int brow = t >> 4, bk4 = (t & 15) * 4;
    const float* srcG = Bg + (size_t)brow * HID + bk4;
    const float* srcU = Bu + (size_t)brow * HID + bk4;
    const unsigned wBo = swz((unsigned)(brow * 128 + bk4 * 2));

    // MFMA fragment LDS byte offsets
    unsigned aoff[3][2], boff[2][2];
#pragma unroll
    for (int mi = 0; mi < 3; mi++)
#pragma unroll
        for (int ks = 0; ks < 2; ks++)
            aoff[mi][ks] = swz((unsigned)((wm * 48 + mi * 16 + fr) * 128 + ks * 64 + fo * 16));
#pragma unroll
    for (int nj = 0; nj < 2; nj++)
#pragma unroll
        for (int ks = 0; ks < 2; ks++)
            boff[nj][ks] = swz((unsigned)((wn * 32 + nj * 16 + fr) * 128 + ks * 64 + fo * 16));

    // A gload geometry: wave w, issue j covers LDS rows (w*3+j)*8..+7
    const int arow_off = lane >> 3;                 // 0..7 (== row&7)
    const int achunk = (lane & 7) ^ arow_off;       // pre-swizzled source chunk

    for (int m0 = m_start; m0 < m_stop; m0 += 384) {
        int rv = m_stop - m0; if (rv > 384) rv = 384;
        const unsigned short* srcA[3];
#pragma unroll
        for (int j = 0; j < 3; j++) {
            int r = (w * 3 + j) * 8 + arow_off;
            int rr = r < rv ? r : rv - 1;
            int tok = routed ? (etk[m0 + rr] >> 1) : (m0 + rr);
            srcA[j] = xb + (size_t)tok * HID + achunk * 8;
        }

        f32x4 ag[3][2], au[3][2];
#pragma unroll
        for (int mi = 0; mi < 3; mi++)
#pragma unroll
            for (int nj = 0; nj < 2; nj++) { ag[mi][nj] = {0.f,0.f,0.f,0.f}; au[mi][nj] = {0.f,0.f,0.f,0.f}; }

        for (int kk = 0; kk < HID / 64; ++kk) {
            const int k0 = kk * 64;
            // stage A (async, register-free)
#pragma unroll
            for (int j = 0; j < 3; j++)
                gload16(srcA[j] + k0, (char*)sA + (unsigned)((w * 3 + j) * 1024));
            // stage B (phase-local regs: load -> cvt -> ds_write, dead before MFMA)
            {
                float4 g4 = *(const float4*)(srcG + k0);
                ushort4 vg;
                vg.x = f2bf(g4.x); vg.y = f2bf(g4.y); vg.z = f2bf(g4.z); vg.w = f2bf(g4.w);
                *(ushort4*)((char*)sBg + wBo) = vg;
                float4 u4 = *(const float4*)(srcU + k0);
                ushort4 vu;
                vu.x = f2bf(u4.x); vu.y = f2bf(u4.y); vu.z = f2bf(u4.z); vu.w = f2bf(u4.w);
                *(ushort4*)((char*)sBu + wBo) = vu;
            }
            __syncthreads();
#pragma unroll
            for (int ks = 0; ks < 2; ++ks) {
                bf16x8 af[3], gf[2], uf[2];
#pragma unroll
                for (int mi = 0; mi < 3; mi++)
                    af[mi] = *(const bf16x8*)((const char*)sA + aoff[mi][ks]);
#pragma unroll
                for (int nj = 0; nj < 2; nj++) {
                    gf[nj] = *(const bf16x8*)((const char*)sBg + boff[nj][ks]);
                    uf[nj] = *(const bf16x8*)((const char*)sBu + boff[nj][ks]);
                }
#pragma unroll
                for (int mi = 0; mi < 3; mi++)
#pragma unroll
                    for (int nj = 0; nj < 2; nj++) {
                        ag[mi][nj] = __builtin_amdgcn_mfma_f32_16x16x32_bf16(af[mi], gf[nj], ag[mi][nj], 0, 0, 0);
                        au[mi][nj] = __builtin_amdgcn_mfma_f32_16x16x32_bf16(af[mi], uf[nj], au[mi][nj], 0, 0, 0);
                    }
            }
            __syncthreads();
        }

        // epilogue: h = silu(g)*u -> stage bf16 [384][64] in sA -> coalesced sweep
#pragma unroll
        for (int mi = 0; mi < 3; mi++)
#pragma unroll
            for (int jj = 0; jj < 4; jj++) {
                int r = wm * 48 + mi * 16 + fo * 4 + jj;
#pragma unroll
                for (int nj = 0; nj < 2; nj++) {
                    int c = wn * 32 + nj * 16 + fr;
                    float g = ag[mi][nj][jj];
                    float u = au[mi][nj][jj];
                    float h = (g / (1.f + __expf(-g))) * u;
                    *(unsigned short*)((char*)sA + swz((unsigned)(r * 128 + c * 2))) = f2bf(h);
                }
            }
        __syncthreads();
#pragma unroll
        for (int q = 0; q < 3; q++) {
            int idx = q * 1024 + t;
            int r = idx >> 3, c = idx & 7;
            if (r < rv) {
                uint4 v = *(const uint4*)((const char*)sA + swz((unsigned)(r * 128 + c * 16)));
                *(uint4*)(outp + (size_t)(obase + m0 + r) * Ntot + n0 + c * 8) = v;
            }
        }
        __syncthreads();
    }
}

// Down GEMM. BM=384, BN=128, BK=64, 1024 thr / 16 waves (8m x 2n).
// Output: bf16 slots[3][TTOK][HID] (slice 0/1 = routed topk slots, slice 2 = shared z).
__global__ __launch_bounds__(1024) void k_down3(
    const unsigned short* __restrict__ abuf, const unsigned short* __restrict__ hbuf,
    const float* __restrict__ wd, const float* __restrict__ sd,
    unsigned short* __restrict__ slots,
    const int* __restrict__ cnt, const int* __restrict__ offs,
    const int* __restrict__ etok, const float* __restrict__ ew) {
    __shared__ alignas(16) unsigned short sA[384 * 64];   // 48 KB
    __shared__ alignas(16) unsigned short sB[128 * 64];   // 16 KB

    const int bx = blockIdx.x;
    const int t = threadIdx.x;
    const int lane = t & 63;
    const int w = t >> 6;
    const int wm = w >> 1, wn = w & 1;
    const int fr = lane & 15, fo = lane >> 4;

    const bool routed = bx < RDWN;
    int n0, m_start, m_stop, K, KT;
    const float* W;
    const unsigned short* Abuf;
    size_t arow0 = 0;
    const int* etk = nullptr; const float* ewe = nullptr;
    if (routed) {
        int e = bx / DWN_NT; n0 = (bx % DWN_NT) * 128;
        int M = cnt[e];
        if (M <= 0) return;
        m_start = 0; m_stop = M;
        K = INTER; KT = INTER / 64;
        W = wd + ((size_t)e * HID + n0) * INTER;
        Abuf = abuf; arow0 = offs[e];
        etk = etok + e * TTOK; ewe = ew + e * TTOK;
    } else {
        int sx = bx - RDWN;
        n0 = (sx % DWN_NT) * 128;
        m_start = (sx / DWN_NT) * 384;
        m_stop = min(TTOK, m_start + 384);
        K = SINTER; KT = SINTER / 64;
        W = sd + (size_t)n0 * SINTER;
        Abuf = hbuf;
    }

    // B staging: thread -> row t>>3 (0..127), 8 floats at (t&7)*8; 16B bf16 ds_write
    const int brow = t >> 3, bk8 = (t & 7) * 8;
    const float* srcB = W + (size_t)brow * K + bk8;
    const unsigned wBo = swz((unsigned)(brow * 128 + bk8 * 2));

    unsigned aoff[3][2], boff[4][2];
#pragma unroll
    for (int mi = 0; mi < 3; mi++)
#pragma unroll
        for (int ks = 0; ks < 2; ks++)
            aoff[mi][ks] = swz((unsigned)((wm * 48 + mi * 16 + fr) * 128 + ks * 64 + fo * 16));
#pragma unroll
    for (int nj = 0; nj < 4; nj++)
#pragma unroll
        for (int ks = 0; ks < 2; ks++)
            boff[nj][ks] = swz((unsigned)((wn * 64 + nj * 16 + fr) * 128 + ks * 64 + fo * 16));

    const int arow_off = lane >> 3;
    const int achunk = (lane & 7) ^ arow_off;

    for (int m0 = m_start; m0 < m_stop; m0 += 384) {
        int rv = m_stop - m0; if (rv > 384) rv = 384;
        const unsigned short* srcA[3];
#pragma unroll
        for (int j = 0; j < 3; j++) {
            int r = (w * 3 + j) * 8 + arow_off;
            int rr = r < rv ? r : rv - 1;
            srcA[j] = Abuf + (arow0 + m0 + rr) * (size_t)K + achunk * 8;
        }

        f32x4 ac[3][4];
#pragma unroll
        for (int mi = 0; mi < 3; mi++)
#pragma unroll
            for (int nj = 0; nj < 4; nj++) ac[mi][nj] = {0.f, 0.f, 0.f, 0.f};

        for (int kk = 0; kk < KT; ++kk) {
            const int k0 = kk * 64;
#pragma unroll
            for (int j = 0; j < 3; j++)
                gload16(srcA[j] + k0, (char*)sA + (unsigned)((w * 3 + j) * 1024));
            {
                float4 b0 = *(const float4*)(srcB + k0);
                float4 b1 = *(const float4*)(srcB + k0 + 4);
                bf16x8 v;
                v[0] = (short)f2bf(b0.x); v[1] = (short)f2bf(b0.y);
                v[2] = (short)f2bf(b0.z); v[3] = (short)f2bf(b0.w);
                v[4] = (short)f2bf(b1.x); v[5] = (short)f2bf(b1.y);
                v[6] = (short)f2bf(b1.z); v[7] = (short)f2bf(b1.w);
                *(bf16x8*)((char*)sB + wBo) = v;
            }
            __syncthreads();
#pragma unroll
            for (int ks = 0; ks < 2; ++ks) {
                bf16x8 af[3], bf[4];
#pragma unroll
                for (int mi = 0; mi < 3; mi++)
                    af[mi] = *(const bf16x8*)((const char*)sA + aoff[mi][ks]);
#pragma unroll
                for (int nj = 0; nj < 4; nj++)
                    bf[nj] = *(const bf16x8*)((const char*)sB + boff[nj][ks]);
#pragma unroll
                for (int mi = 0; mi < 3; mi++)
#pragma unroll
                    for (int nj = 0; nj < 4; nj++)
                        ac[mi][nj] = __builtin_amdgcn_mfma_f32_16x16x32_bf16(af[mi], bf[nj], ac[mi][nj], 0, 0, 0);
            }
            __syncthreads();
        }

        // epilogue: 2 column-passes of 64 through sA (waves with wn==p own cols p*64..p*64+63)
#pragma unroll
        for (int p = 0; p < 2; p++) {
            if (wn == p) {
#pragma unroll
                for (int mi = 0; mi < 3; mi++)
#pragma unroll
                    for (int jj = 0; jj < 4; jj++) {
                        int r = wm * 48 + mi * 16 + fo * 4 + jj;
                        float wt = (routed && r < rv) ? ewe[m0 + r] : 1.f;
#pragma unroll
                        for (int nj = 0; nj < 4; nj++) {
                            int c = nj * 16 + fr;
                            *(unsigned short*)((char*)sA + swz((unsigned)(r * 128 + c * 2))) =
                                f2bf(ac[mi][nj][jj] * wt);
                        }
                    }
            }
            __syncthreads();
#pragma unroll
            for (int q = 0; q < 3; q++) {
                int idx = q * 1024 + t;
                int r = idx >> 3, c = idx & 7;
                if (r < rv) {
                    uint4 v = *(const uint4*)((const char*)sA + swz((unsigned)(r * 128 + c * 16)));
                    int tok, slice;
                    if (routed) { int entry = etk[m0 + r]; tok = entry >> 1; slice = entry & 1; }
                    else        { tok = m0 + r; slice = 2; }
                    *(uint4*)(slots + ((size_t)slice * TTOK + tok) * HID + n0 + p * 64 + c * 8) = v;
                }
            }
            __syncthreads();
        }
    }
}

__global__ __launch_bounds__(256) void k_final(float* __restrict__ out,
                                               const unsigned short* __restrict__ slots) {
    size_t i = ((size_t)blockIdx.x * 256 + threadIdx.x) * 8;
    u16x8 s0 = *(const u16x8*)(slots + i);
    u16x8 s1 = *(const u16x8*)(slots + (size_t)TTOK * HID + i);
    u16x8 s2 = *(const u16x8*)(slots + (size_t)2 * TTOK * HID + i);
    float4 o0, o1;
    o0.x = bf2f(s0[0]) + bf2f(s1[0]) + bf2f(s2[0]);
    o0.y = bf2f(s0[1]) + bf2f(s1[1]) + bf2f(s2[1]);
    o0.z = bf2f(s0[2]) + bf2f(s1[2]) + bf2f(s2[2]);
    o0.w = bf2f(s0[3]) + bf2f(s1[3]) + bf2f(s2[3]);
    o1.x = bf2f(s0[4]) + bf2f(s1[4]) + bf2f(s2[4]);
    o1.y = bf2f(s0[5]) + bf2f(s1[5]) + bf2f(s2[5]);
    o1.z = bf2f(s0[6]) + bf2f(s1[6]) + bf2f(s2[6]);
    o1.w = bf2f(s0[7]) + bf2f(s1[7]) + bf2f(s2[7]);
    *(float4*)(out + i) = o0;
    *(float4*)(out + i + 4) = o1;
}

extern "C" void kernel_launch(void* const* d_in, const int* in_sizes, int n_in,
                              void* d_out, int out_size, void* d_ws, size_t ws_size,
                              hipStream_t stream) {
    const float* x = (const float*)d_in[0];
    const float* gate_w = (const float*)d_in[1];
    const float* cls_w = (const float*)d_in[2];
    const float* escale = (const float*)d_in[3];
    const float* ebias = (const float*)d_in[4];
    const float* wg = (const float*)d_in[5];
    const float* wu = (const float*)d_in[6];
    const float* wd = (const float*)d_in[7];
    const float* sg = (const float*)d_in[8];
    const float* su = (const float*)d_in[9];
    const float* sd = (const float*)d_in[10];
    float* out = (float*)d_out;

    char* ws = (char*)d_ws;
    size_t o = 0;
    auto alloc = [&](size_t bytes) {
        char* p = ws + o;
        o += (bytes + 255) & ~(size_t)255;
        return p;
    };
    unsigned short* xb    = (unsigned short*)alloc((size_t)TTOK * HID * 2);        // 8 MB
    unsigned short* hbuf  = (unsigned short*)alloc((size_t)TTOK * SINTER * 2);     // 11.5 MB
    unsigned short* abuf  = (unsigned short*)alloc((size_t)2 * TTOK * INTER * 2);  // 11.5 MB
    unsigned short* slots = (unsigned short*)alloc((size_t)3 * TTOK * HID * 2);    // 24 MB
    int* cnt              = (int*)alloc(256);
    int* offs             = (int*)alloc(256);
    int* etok             = (int*)alloc((size_t)NEXP * TTOK * 4);
    float* ew             = (float*)alloc((size_t)NEXP * TTOK * 4);

    k_zero<<<1, 64, 0, stream>>>(cnt);
    k_xcvt<<<2048, 256, 0, stream>>>(x, xb);
    k_router<<<512, 256, 0, stream>>>(x, gate_w, cls_w, escale, ebias, cnt, etok, ew);
    k_offsets<<<1, 64, 0, stream>>>(cnt, offs);
    k_glu3<<<RGLU + SGLU_N * SGLU_M, 1024, 0, stream>>>(
        xb, wg, wu, sg, su, abuf, hbuf, cnt, offs, etok);
    k_down3<<<RDWN + DWN_NT * SDWN_M, 1024, 0, stream>>>(
        abuf, hbuf, wd, sd, slots, cnt, offs, etok, ew);
    k_final<<<2048, 256, 0, stream>>>(out, slots);
}